// Round 1
// 172.870 us; speedup vs baseline: 1.0951x; 1.0951x over previous
//
#include <hip/hip_runtime.h>
#include <hip/hip_bf16.h>

typedef __bf16 bf16_t;
typedef __attribute__((ext_vector_type(8))) __bf16 bf16x8;
typedef __attribute__((ext_vector_type(4))) __bf16 bf16x4;
typedef __attribute__((ext_vector_type(4))) float floatx4;

// B=8, N=4096, D=CV=128. fp32 in/out; bf16 MFMA compute, fp32 accumulate.
static constexpr int NSEQ = 4096;
static constexpr int DIM  = 128;
static constexpr int BATCH = 8;
static constexpr size_t NELEM = (size_t)BATCH * NSEQ * DIM;
static constexpr size_t WS_NEED = 2 * NELEM * sizeof(bf16_t);   // Kb + Vt = 16 MiB

// ---- split-K decomposition: chunk = 16 key-tiles (1024 keys) ----
static constexpr int CHUNK_T = 16;
static constexpr int NSLOT   = 160;   // per batch: sum_{t<64} ceil((t+1)/16)
static constexpr size_t PART_FLOATS = (size_t)BATCH * NSLOT * 64 * 128;  // O partials
static constexpr size_t LSUM_FLOATS = (size_t)BATCH * NSLOT * 64;        // l partials
static constexpr size_t WS_SPLITK =
    WS_NEED + (PART_FLOATS + LSUM_FLOATS) * sizeof(float);               // ~59 MB

// 1/sqrt(128) * log2(e); folded into Q so the inner loop is bare exp2.
static constexpr float SCALE_LOG2E = 0.08838834764831845f * 1.4426950408889634f;

// S(qt) = sum_{t<qt} ceil((t+1)/16) ; closed form with g=qt/16, r=qt%16
__device__ __forceinline__ int slot_base(int qt) {
  int g = qt >> 4, r = qt & 15;
  return qt + 8 * g * (g - 1) + r * g;
}

// async global->LDS, 16B per lane; LDS dest = wave-uniform base + lane*16
__device__ __forceinline__ void gld16(bf16_t* l, const bf16_t* g) {
  __builtin_amdgcn_global_load_lds(
      (const __attribute__((address_space(1))) unsigned int*)g,
      (__attribute__((address_space(3))) unsigned int*)l, 16, 0, 0);
}

__device__ __forceinline__ bf16x8 ld8_f32s(const float* p, float s) {
  float4 a = *(const float4*)p;
  float4 b = *(const float4*)(p + 4);
  bf16x8 r = {(__bf16)(a.x * s), (__bf16)(a.y * s), (__bf16)(a.z * s), (__bf16)(a.w * s),
              (__bf16)(b.x * s), (__bf16)(b.y * s), (__bf16)(b.z * s), (__bf16)(b.w * s)};
  return r;
}

// ---------------- prep: K fp32->bf16, V fp32 -> Vt bf16 [B][dim][key] ----------------
// All-vector IO, no LDS. V transpose is done in-register: each thread owns 4 dim-rows
// x 8 keys (8x float4 loads, 4x bf16x8 stores). Scattered 16B stores merge in L2
// (batch->XCD affinity keeps the active Vt slice ~1MB << 4MB L2).

__global__ __launch_bounds__(256)
void prep_kernel(const float* __restrict__ K, const float* __restrict__ V,
                 bf16_t* __restrict__ Kb, bf16_t* __restrict__ Vt) {
  const int bid = blockIdx.x;
  if (bid < 1536) {                       // K convert, grid-stride
    const size_t n4 = NELEM / 4;
    for (size_t i = (size_t)bid * 256 + threadIdx.x; i < n4; i += (size_t)1536 * 256) {
      float4 k = ((const float4*)K)[i];
      bf16x4 kv = {(__bf16)k.x, (__bf16)k.y, (__bf16)k.z, (__bf16)k.w};
      ((bf16x4*)Kb)[i] = kv;
    }
  } else {                                // V transpose+convert
    const int id = bid - 1536;            // 0..511
    const int b  = id & 7;                // batch -> XCD affinity
    const int kt = id >> 3;               // 0..63 : 64-key tile
    const int d4 = (int)threadIdx.x & 31; // dim group (4 dims)
    const int kg = (int)threadIdx.x >> 5; // 0..7   : 8-key group
    const float* src = V + ((size_t)(b * NSEQ + kt * 64 + kg * 8) * DIM) + d4 * 4;
    bf16x8 o0, o1, o2, o3;
    #pragma unroll
    for (int j = 0; j < 8; ++j) {
      float4 v = *(const float4*)(src + (size_t)j * DIM);
      o0[j] = (__bf16)v.x; o1[j] = (__bf16)v.y;
      o2[j] = (__bf16)v.z; o3[j] = (__bf16)v.w;
    }
    bf16_t* dst = Vt + ((size_t)b * DIM + d4 * 4) * NSEQ + kt * 64 + kg * 8;
    *(bf16x8*)(dst)            = o0;
    *(bf16x8*)(dst + NSEQ)     = o1;
    *(bf16x8*)(dst + 2 * NSEQ) = o2;
    *(bf16x8*)(dst + 3 * NSEQ) = o3;
  }
}

// ---------------- shared per-tile compute (16q x 64k per wave) ----------------

template <bool MASK>
__device__ __forceinline__ void tile_compute(
    const bf16_t* __restrict__ kbuf, const bf16_t* __restrict__ vbuf,
    bf16_t* __restrict__ pl, const bf16x8 (&qf)[4],
    int l16, int quad, int wq, floatx4 (&acc)[8], float (&lsum)[4]) {
  // ---- S = Q K^T (16q x 64k), LDS K reads XOR-swizzled ----
  floatx4 s[4];
  #pragma unroll
  for (int c4 = 0; c4 < 4; ++c4) s[c4] = (floatx4){0.f, 0.f, 0.f, 0.f};
  #pragma unroll
  for (int c4 = 0; c4 < 4; ++c4) {
    const bf16_t* krow = kbuf + (c4 * 16 + l16) * DIM;
    #pragma unroll
    for (int d = 0; d < 4; ++d) {
      bf16x8 kf = *(const bf16x8*)(krow + (((4 * d + quad) ^ l16) * 8));
      s[c4] = __builtin_amdgcn_mfma_f32_16x16x32_bf16(qf[d], kf, s[c4], 0, 0, 0);
    }
  }
  // ---- p = exp2(s); stage P (C-layout -> A-layout via per-wave LDS) ----
  #pragma unroll
  for (int c4 = 0; c4 < 4; ++c4) {
    #pragma unroll
    for (int r = 0; r < 4; ++r) {
      float v = s[c4][r];
      if constexpr (MASK)
        v = (c4 * 16 + l16 <= wq + quad * 4 + r) ? v : -3.0e38f;  // exp2 -> 0
      float p = __builtin_amdgcn_exp2f(v);
      lsum[r] += p;                       // deferred l-reduction
      pl[(quad * 4 + r) * 72 + c4 * 16 + l16] = (__bf16)p;
    }
  }
  asm volatile("s_waitcnt lgkmcnt(0)" ::: "memory");  // drain P writes (in-wave)
  bf16x8 pfA = *(const bf16x8*)(pl + l16 * 72 + quad * 8);
  bf16x8 pfB = *(const bf16x8*)(pl + l16 * 72 + 32 + quad * 8);
  // ---- O += P(16x64) * V(64x128), LDS V reads XOR-swizzled ----
  #pragma unroll
  for (int c = 0; c < 8; ++c) {
    const bf16_t* vrow = vbuf + (c * 16 + l16) * 64;
    bf16x8 vfA = *(const bf16x8*)(vrow + ((quad ^ (l16 & 7)) * 8));
    bf16x8 vfB = *(const bf16x8*)(vrow + (((quad + 4) ^ (l16 & 7)) * 8));
    acc[c] = __builtin_amdgcn_mfma_f32_16x16x32_bf16(pfA, vfA, acc[c], 0, 0, 0);
    acc[c] = __builtin_amdgcn_mfma_f32_16x16x32_bf16(pfB, vfB, acc[c], 0, 0, 0);
  }
}

// ---------------- split-K attention: block = (batch, 64q tile, key chunk) ----------------

__global__ __launch_bounds__(256)
void causal_attn_splitk(const float* __restrict__ Qf, const bf16_t* __restrict__ Kb,
                        const bf16_t* __restrict__ Vt, float* __restrict__ Out,
                        float* __restrict__ Pp, float* __restrict__ Ls) {
  __shared__ __align__(16) bf16_t Kbuf[64 * DIM];   // 16 KB
  __shared__ __align__(16) bf16_t Vbuf[DIM * 64];   // 16 KB
  __shared__ __align__(16) bf16_t Pbuf[4][16 * 72]; //  9 KB  -> 41984 B, 3 blocks/CU

  const int b = (int)blockIdx.x & 7;                 // batch -> XCD affinity
  int s = (NSLOT - 1) - ((int)blockIdx.x >> 3);      // biggest-qt chunks dispatched first
  int qt = 63, cch = 0;
  {
    int acc0 = 0;                                    // scalar decode s -> (qt, chunk)
    for (int t = 0; t < 64; ++t) {
      int nch = (t >> 4) + 1;
      if (s < acc0 + nch) { qt = t; cch = s - acc0; break; }
      acc0 += nch;
    }
  }
  const int  nchq   = (qt >> 4) + 1;
  const int  t0     = cch * CHUNK_T;                  // first key-tile of chunk
  const int  nts    = min(CHUNK_T, qt + 1 - t0);      // tiles in this chunk
  const bool isLast = (cch == nchq - 1);              // chunk holding the diagonal

  const int tid  = (int)threadIdx.x;
  const int wave = tid >> 6;
  const int lane = tid & 63;
  const int l16  = lane & 15;
  const int quad = lane >> 4;
  const int wq   = wave * 16;

  // Q fragments: fp32 read, scale folded, A-layout A[m=l16][k=quad*8+j]
  bf16x8 qf[4];
  {
    const float* qrow = Qf + ((size_t)b * NSEQ + qt * 64 + wq + l16) * DIM + quad * 8;
    #pragma unroll
    for (int d = 0; d < 4; ++d) qf[d] = ld8_f32s(qrow + 32 * d, SCALE_LOG2E);
  }

  // staging addresses (wave w stages K rows 16w..16w+15, V dims 32w..32w+31)
  const bf16_t* kg0 = Kb + ((size_t)b * NSEQ + 16 * wave) * DIM;
  const bf16_t* vg0 = Vt + ((size_t)b * DIM + 32 * wave) * NSEQ;
  int koff[4], voff[4];
  #pragma unroll
  for (int i = 0; i < 4; ++i) {
    const int krow = 4 * i + (lane >> 4);
    koff[i] = krow * DIM + (((lane & 15) ^ (krow & 15)) * 8);
    const int vrow = 8 * i + (lane >> 3);
    voff[i] = vrow * NSEQ + (((lane & 7) ^ ((lane >> 3) & 7)) * 8);
  }
  bf16_t* kl = Kbuf + 16 * wave * DIM;
  bf16_t* vl = Vbuf + 32 * wave * 64;
  bf16_t* pl = Pbuf[wave];

  floatx4 acc[8];
  #pragma unroll
  for (int c = 0; c < 8; ++c) acc[c] = (floatx4){0.f, 0.f, 0.f, 0.f};
  float lsum[4] = {0.f, 0.f, 0.f, 0.f};

  const int nfull = nts - (isLast ? 1 : 0);           // unmasked tiles
  for (int kt = 0; kt < nfull; ++kt) {
    const int kb = (t0 + kt) * 64;
    #pragma unroll
    for (int i = 0; i < 4; ++i) gld16(kl + i * 512, kg0 + (size_t)kb * DIM + koff[i]);
    #pragma unroll
    for (int i = 0; i < 4; ++i) gld16(vl + i * 512, vg0 + kb + voff[i]);
    __syncthreads();
    tile_compute<false>(Kbuf, Vbuf, pl, qf, l16, quad, wq, acc, lsum);
    __syncthreads();
  }
  if (isLast) {                                       // diagonal (masked) tile
    const int kb = qt * 64;
    #pragma unroll
    for (int i = 0; i < 4; ++i) gld16(kl + i * 512, kg0 + (size_t)kb * DIM + koff[i]);
    #pragma unroll
    for (int i = 0; i < 4; ++i) gld16(vl + i * 512, vg0 + kb + voff[i]);
    __syncthreads();
    tile_compute<true>(Kbuf, Vbuf, pl, qf, l16, quad, wq, acc, lsum);
  }

  // ---- l-reduction over 16 key-lanes ----
  float lred[4];
  #pragma unroll
  for (int r = 0; r < 4; ++r) {
    float s2 = lsum[r];
    #pragma unroll
    for (int off = 1; off < 16; off <<= 1) s2 += __shfl_xor(s2, off, 64);
    lred[r] = s2;
  }

  if (nchq == 1) {                                    // qt <= 15: direct output
    float* orow = Out + ((size_t)b * NSEQ + qt * 64 + wq + quad * 4) * DIM + l16;
    #pragma unroll
    for (int c = 0; c < 8; ++c) {
      #pragma unroll
      for (int r = 0; r < 4; ++r)
        orow[(size_t)r * DIM + c * 16] = acc[c][r] * (1.0f / lred[r]);
    }
  } else {                                            // write unnormalized partials
    const int slot = b * NSLOT + slot_base(qt) + cch;
    float* pb = Pp + (size_t)slot * (64 * 128) + ((size_t)(wq + quad * 4)) * 128 + l16;
    #pragma unroll
    for (int c = 0; c < 8; ++c) {
      #pragma unroll
      for (int r = 0; r < 4; ++r)
        pb[(size_t)r * 128 + c * 16] = acc[c][r];
    }
    if (l16 == 0) {
      #pragma unroll
      for (int r = 0; r < 4; ++r)
        Ls[(size_t)slot * 64 + wq + quad * 4 + r] = lred[r];
    }
  }
}

// ---------------- combine: sum chunk partials, normalize, store (qt >= 16) ----------------

__global__ __launch_bounds__(256)
void combine_kernel(const float* __restrict__ Pp, const float* __restrict__ Ls,
                    float* __restrict__ Out) {
  const int e  = (int)blockIdx.x;       // 8 batches x 48 qtiles
  const int b  = e & 7;
  const int qt = 16 + (e >> 3);
  const int s0 = b * NSLOT + slot_base(qt);
  const int nch = (qt >> 4) + 1;        // 2..4
  const int t = (int)threadIdx.x;
  #pragma unroll
  for (int j = 0; j < 8; ++j) {
    const int idx = j * 256 + t;        // 0..2047 float4s
    const int q   = idx >> 5;
    const int d4  = idx & 31;
    float4 v = {0.f, 0.f, 0.f, 0.f};
    float  l = 0.f;
    for (int ch = 0; ch < nch; ++ch) {
      const float* pc = Pp + (size_t)(s0 + ch) * 8192 + (size_t)q * 128 + d4 * 4;
      float4 a = *(const float4*)pc;
      v.x += a.x; v.y += a.y; v.z += a.z; v.w += a.w;
      l += Ls[(size_t)(s0 + ch) * 64 + q];
    }
    const float inv = 1.0f / l;
    float4 r = {v.x * inv, v.y * inv, v.z * inv, v.w * inv};
    *(float4*)(Out + ((size_t)b * NSEQ + qt * 64 + q) * DIM + d4 * 4) = r;
  }
}

// ---------------- middle tier: previous best kernel (ws >= 16.8 MB only) ----------------

__global__ __launch_bounds__(256)
void causal_attn_kernel(const float* __restrict__ Qf, const bf16_t* __restrict__ Kb,
                        const bf16_t* __restrict__ Vt, float* __restrict__ Out) {
  __shared__ __align__(16) bf16_t Kbuf[64 * DIM];
  __shared__ __align__(16) bf16_t Vbuf[DIM * 64];
  __shared__ __align__(16) bf16_t Pbuf[4][16 * 72];

  const int half = blockIdx.x >> 8;
  const int idx  = blockIdx.x & 255;
  const int b    = idx & 7;
  const int q32  = idx >> 3;
  const int qt64 = half ? q32 : 63 - q32;

  const int tid  = (int)threadIdx.x;
  const int wave = tid >> 6;
  const int lane = tid & 63;
  const int l16  = lane & 15;
  const int quad = lane >> 4;
  const int wq   = wave * 16;

  bf16x8 qf[4];
  {
    const float* qrow = Qf + ((size_t)b * NSEQ + qt64 * 64 + wq + l16) * DIM + quad * 8;
    #pragma unroll
    for (int d = 0; d < 4; ++d) qf[d] = ld8_f32s(qrow + 32 * d, SCALE_LOG2E);
  }

  const bf16_t* kg0 = Kb + ((size_t)b * NSEQ + 16 * wave) * DIM;
  const bf16_t* vg0 = Vt + ((size_t)b * DIM + 32 * wave) * NSEQ;
  int koff[4], voff[4];
  #pragma unroll
  for (int i = 0; i < 4; ++i) {
    const int krow = 4 * i + (lane >> 4);
    koff[i] = krow * DIM + (((lane & 15) ^ (krow & 15)) * 8);
    const int vrow = 8 * i + (lane >> 3);
    voff[i] = vrow * NSEQ + (((lane & 7) ^ ((lane >> 3) & 7)) * 8);
  }
  bf16_t* kl = Kbuf + 16 * wave * DIM;
  bf16_t* vl = Vbuf + 32 * wave * 64;
  bf16_t* pl = Pbuf[wave];

  floatx4 acc[8];
  #pragma unroll
  for (int c = 0; c < 8; ++c) acc[c] = (floatx4){0.f, 0.f, 0.f, 0.f};
  float lsum[4] = {0.f, 0.f, 0.f, 0.f};

  const int nk = qt64 + 1;
  for (int kt = 0; kt < nk - 1; ++kt) {
    const int kb = kt * 64;
    #pragma unroll
    for (int i = 0; i < 4; ++i) gld16(kl + i * 512, kg0 + (size_t)kb * DIM + koff[i]);
    #pragma unroll
    for (int i = 0; i < 4; ++i) gld16(vl + i * 512, vg0 + kb + voff[i]);
    __syncthreads();
    tile_compute<false>(Kbuf, Vbuf, pl, qf, l16, quad, wq, acc, lsum);
    __syncthreads();
  }
  {
    const int kb = (nk - 1) * 64;
    #pragma unroll
    for (int i = 0; i < 4; ++i) gld16(kl + i * 512, kg0 + (size_t)kb * DIM + koff[i]);
    #pragma unroll
    for (int i = 0; i < 4; ++i) gld16(vl + i * 512, vg0 + kb + voff[i]);
    __syncthreads();
    tile_compute<true>(Kbuf, Vbuf, pl, qf, l16, quad, wq, acc, lsum);
  }

  float inv_l[4];
  #pragma unroll
  for (int r = 0; r < 4; ++r) {
    float s = lsum[r];
    #pragma unroll
    for (int off = 1; off < 16; off <<= 1) s += __shfl_xor(s, off, 64);
    inv_l[r] = 1.0f / s;
  }
  float* orow = Out + ((size_t)b * NSEQ + qt64 * 64 + wq + quad * 4) * DIM + l16;
  #pragma unroll
  for (int c = 0; c < 8; ++c) {
    #pragma unroll
    for (int r = 0; r < 4; ++r)
      orow[(size_t)r * DIM + c * 16] = acc[c][r] * inv_l[r];
  }
}

// ---------------- fallback (no workspace): fp32 direct ----------------

__global__ __launch_bounds__(256)
void causal_attn_fb(const float* __restrict__ Qf, const float* __restrict__ Kf,
                    const float* __restrict__ Vf, float* __restrict__ Out) {
  __shared__ bf16_t p_lds[4][16 * 72];
  const int bid = blockIdx.x, t = bid >> 3, b = bid & 7;
  const int tid = (int)threadIdx.x, wave = tid >> 6, lane = tid & 63;
  const int l16 = lane & 15, quad = lane >> 4;
  const int qtile = (wave < 2) ? t : (127 - t);
  const int q_base = qtile * 32 + (wave & 1) * 16;

  bf16x8 qf[4];
  const float* qrow = Qf + ((size_t)b * NSEQ + q_base + l16) * DIM + quad * 8;
  #pragma unroll
  for (int d = 0; d < 4; ++d) qf[d] = ld8_f32s(qrow + 32 * d, SCALE_LOG2E);

  floatx4 acc[8];
  #pragma unroll
  for (int c = 0; c < 8; ++c) acc[c] = (floatx4){0.f, 0.f, 0.f, 0.f};
  float lsum[4] = {0.f, 0.f, 0.f, 0.f};
  bf16_t* pl = p_lds[wave];
  const int ntiles = (q_base + 16 + 63) >> 6;

  for (int kt = 0; kt < ntiles; ++kt) {
    const int kb = kt * 64;
    floatx4 s[4];
    #pragma unroll
    for (int c4 = 0; c4 < 4; ++c4) s[c4] = (floatx4){0.f, 0.f, 0.f, 0.f};
    const float* kbase = Kf + ((size_t)b * NSEQ + kb + l16) * DIM + quad * 8;
    #pragma unroll
    for (int c4 = 0; c4 < 4; ++c4) {
      #pragma unroll
      for (int d = 0; d < 4; ++d) {
        bf16x8 kf = ld8_f32s(kbase + (size_t)c4 * 16 * DIM + 32 * d, 1.0f);
        s[c4] = __builtin_amdgcn_mfma_f32_16x16x32_bf16(qf[d], kf, s[c4], 0, 0, 0);
      }
    }
    #pragma unroll
    for (int c4 = 0; c4 < 4; ++c4) {
      #pragma unroll
      for (int r = 0; r < 4; ++r) {
        float v = s[c4][r];
        const int qi = q_base + quad * 4 + r;
        v = (kb + c4 * 16 + l16 <= qi) ? v : -3.0e38f;
        float p = __builtin_amdgcn_exp2f(v);
        lsum[r] += p;
        pl[(quad * 4 + r) * 72 + c4 * 16 + l16] = (__bf16)p;
      }
    }
    asm volatile("s_waitcnt lgkmcnt(0)" ::: "memory");
    bf16x8 pfA = *(const bf16x8*)(pl + l16 * 72 + quad * 8);
    bf16x8 pfB = *(const bf16x8*)(pl + l16 * 72 + 32 + quad * 8);
    const float* vb = Vf + ((size_t)b * NSEQ + kb) * DIM;
    #pragma unroll
    for (int c = 0; c < 8; ++c) {
      bf16x8 vfA, vfB;
      #pragma unroll
      for (int j = 0; j < 8; ++j) {
        vfA[j] = (__bf16)vb[(size_t)(quad * 8 + j) * DIM + c * 16 + l16];
        vfB[j] = (__bf16)vb[(size_t)(32 + quad * 8 + j) * DIM + c * 16 + l16];
      }
      acc[c] = __builtin_amdgcn_mfma_f32_16x16x32_bf16(pfA, vfA, acc[c], 0, 0, 0);
      acc[c] = __builtin_amdgcn_mfma_f32_16x16x32_bf16(pfB, vfB, acc[c], 0, 0, 0);
    }
  }
  float inv_l[4];
  #pragma unroll
  for (int r = 0; r < 4; ++r) {
    float s = lsum[r];
    #pragma unroll
    for (int off = 1; off < 16; off <<= 1) s += __shfl_xor(s, off, 64);
    inv_l[r] = 1.0f / s;
  }
  float* orow = Out + ((size_t)b * NSEQ + q_base + quad * 4) * DIM + l16;
  #pragma unroll
  for (int c = 0; c < 8; ++c) {
    #pragma unroll
    for (int r = 0; r < 4; ++r)
      orow[(size_t)r * DIM + c * 16] = acc[c][r] * inv_l[r];
  }
}

extern "C" void kernel_launch(void* const* d_in, const int* in_sizes, int n_in,
                              void* d_out, int out_size, void* d_ws, size_t ws_size,
                              hipStream_t stream) {
  const float* Q = (const float*)d_in[0];
  const float* K = (const float*)d_in[1];
  const float* V = (const float*)d_in[2];
  float* Out = (float*)d_out;
  (void)in_sizes; (void)n_in; (void)out_size;

  dim3 block(256);
  if (ws_size >= WS_SPLITK) {
    bf16_t* Kb = (bf16_t*)d_ws;
    bf16_t* Vt = Kb + NELEM;
    float*  Pp = (float*)((char*)d_ws + WS_NEED);
    float*  Ls = Pp + PART_FLOATS;
    prep_kernel<<<dim3(2048), block, 0, stream>>>(K, V, Kb, Vt);
    causal_attn_splitk<<<dim3(BATCH * NSLOT), block, 0, stream>>>(Q, Kb, Vt, Out, Pp, Ls);
    combine_kernel<<<dim3(BATCH * 48), block, 0, stream>>>(Pp, Ls, Out);
  } else if (ws_size >= WS_NEED) {
    bf16_t* Kb = (bf16_t*)d_ws;
    bf16_t* Vt = Kb + NELEM;
    prep_kernel<<<dim3(2048), block, 0, stream>>>(K, V, Kb, Vt);
    causal_attn_kernel<<<dim3(512), block, 0, stream>>>(Q, Kb, Vt, Out);
  } else {
    causal_attn_fb<<<dim3(512), block, 0, stream>>>(Q, K, V, Out);
  }
}